// Round 6
// baseline (168.320 us; speedup 1.0000x reference)
//
#include <hip/hip_runtime.h>
#include <math.h>

// Problem constants: B=4, H=W=1024, GH=GW=16, GD=8, C=12
// ws layout: gridbuf[((b*16+gh)*16+gw)*96 + z*12 + c], then params[81]
// params: [w_r x16][w_g x16][w_b x16][bias x16][g2w x16][g2b]

#define GRIDBUF_FLOATS (4 * 16 * 16 * 96)
#define CELL_STRIDE 100   // padded from 96: banks shift by 4 per wc

typedef float  vfloat4 __attribute__((ext_vector_type(4)));
typedef float  f2      __attribute__((ext_vector_type(2)));
typedef int    i2      __attribute__((ext_vector_type(2)));

__device__ inline f2 splat2(float x) { f2 v; v.x = x; v.y = x; return v; }

// packed tanh on a pair: t = sign(x) * (1 - 2/(exp(2|x|)+1))
__device__ inline f2 fast_tanh2(f2 x) {
    f2 ax = __builtin_elementwise_abs(x);
    f2 xx = ax + ax;
    f2 e;
    e.x = __expf(xx.x);
    e.y = __expf(xx.y);
    f2 ep1 = e + splat2(1.0f);
    f2 r;
    r.x = __builtin_amdgcn_rcpf(ep1.x);
    r.y = __builtin_amdgcn_rcpf(ep1.y);
    f2 t = splat2(1.0f) - (r + r);          // in [0,1], e=inf -> t=1
    i2 sgn = __builtin_bit_cast(i2, x) & (i2){(int)0x80000000, (int)0x80000000};
    return __builtin_bit_cast(f2, __builtin_bit_cast(i2, t) | sgn);
}

// ---------------- Kernel 1: grid coefficients + folded guide params ----------
__global__ __launch_bounds__(128) void coeff_kernel(
    const float* __restrict__ lf,    // (B,64,16,16)
    const float* __restrict__ gf,    // (B,64)
    const float* __restrict__ fw,    // (96,64)
    const float* __restrict__ fb,    // (96,)
    const float* __restrict__ g1w,   // (16,3)
    const float* __restrict__ g1b,   // (16,)
    const float* __restrict__ bng,
    const float* __restrict__ bnb,
    const float* __restrict__ bnm,
    const float* __restrict__ bnv,
    const float* __restrict__ g2w,   // (1,16)
    const float* __restrict__ g2b,   // (1,)
    float* __restrict__ gridbuf,     // (B,16,16,96)
    float* __restrict__ params)      // 81 floats
{
    __shared__ float fused[64];
    const int blk = blockIdx.x;       // b*256 + pos
    const int b   = blk >> 8;
    const int pos = blk & 255;
    const int t   = threadIdx.x;

    if (t < 64) {
        float v = lf[(b * 64 + t) * 256 + pos] + gf[b * 64 + t];
        fused[t] = v > 0.0f ? v : 0.0f;
    }
    __syncthreads();

    if (t < 96) {
        float acc = fb[t];
        const float* wrow = fw + t * 64;
#pragma unroll
        for (int i = 0; i < 64; ++i) acc = fmaf(wrow[i], fused[i], acc);
        gridbuf[blk * 96 + t] = acc;
    }

    if (blk == 0 && t >= 96 && t < 112) {
        int k = t - 96;
        float a = bng[k] * rsqrtf(bnv[k] + 1e-5f);
        params[k]      = g1w[k * 3 + 0] * a;
        params[16 + k] = g1w[k * 3 + 1] * a;
        params[32 + k] = g1w[k * 3 + 2] * a;
        params[48 + k] = (g1b[k] - bnm[k]) * a + bnb[k];
        params[64 + k] = g2w[k];
        if (k == 0) params[80] = g2b[0];
    }
}

// ---------------- Kernel 2: guide + bilateral slice + apply + tanh -----------
// R4 structure: one block per image row (4096 blocks), 256 threads, 4 px/thread.
// __launch_bounds__(256,8): cap at 64 VGPR -> 8 waves/SIMD (32 waves/CU)
// (R4 measured VGPR=68 -> 7 waves/SIMD; this kernel is latency-bound, R5 showed
//  occupancy dominates prologue amortization).
__global__ __launch_bounds__(256, 8) void slice_apply_kernel(
    const float* __restrict__ fullres,  // (B,3,1024,1024)
    const float* __restrict__ gridbuf,  // (B,16,16,96)
    const float* __restrict__ params,   // 81 floats (uniform -> s_load)
    float* __restrict__ out)            // (B,3,1024,1024)
{
    __shared__ __align__(16) float hrow[16 * CELL_STRIDE];  // padded h-lerped row

    const int t = threadIdx.x;
    const int b = blockIdx.x >> 10;
    const int y = blockIdx.x & 1023;

    // h interpolation (constant for the whole row)
    const int h0i  = (y < 32) ? -1 : ((y - 32) >> 6);
    const float fh = ((float)y * 0.015625f + (0.0078125f - 0.5f)) - (float)h0i;
    const int hc0  = h0i < 0 ? 0 : h0i;
    const int hc1  = (h0i + 1) > 15 ? 15 : (h0i + 1);

    const float* row0 = gridbuf + (b * 256 + hc0 * 16) * 96;
    const float* row1 = gridbuf + (b * 256 + hc1 * 16) * 96;
    const float wfh0 = 1.0f - fh;
#pragma unroll
    for (int i4 = t; i4 < 384; i4 += 256) {
        const int i   = i4 << 2;
        const int wc  = i / 96;
        const int rem = i - wc * 96;
        float4 a = *(const float4*)(row0 + i);
        float4 c = *(const float4*)(row1 + i);
        float4 r;
        r.x = fmaf(wfh0, a.x, fh * c.x);
        r.y = fmaf(wfh0, a.y, fh * c.y);
        r.z = fmaf(wfh0, a.z, fh * c.z);
        r.w = fmaf(wfh0, a.w, fh * c.w);
        *(float4*)(hrow + wc * CELL_STRIDE + rem) = r;
    }
    __syncthreads();

    const int xb = t << 2;                      // 4 pixels per thread
    const int pixbase = (y << 10) + xb;
    const int planeB = (b * 3) << 20;

    const float4 r4 = *(const float4*)(fullres + planeB + (0 << 20) + pixbase);
    const float4 g4 = *(const float4*)(fullres + planeB + (1 << 20) + pixbase);
    const float4 b4 = *(const float4*)(fullres + planeB + (2 << 20) + pixbase);

    // w cell indices: uniform across this thread's 4 pixels
    const int w0i = (xb < 32) ? -1 : ((xb - 32) >> 6);
    const int wc0 = w0i < 0 ? 0 : w0i;
    const int wc1 = (w0i + 1) > 15 ? 15 : (w0i + 1);
    const float fw0 = (float)xb * 0.015625f + (0.0078125f - 0.5f) - (float)w0i;
    const float* cell0 = hrow + wc0 * CELL_STRIDE;
    const float* cell1 = hrow + wc1 * CELL_STRIDE;

    vfloat4 vR, vG, vB;

#pragma unroll
    for (int pp = 0; pp < 2; ++pp) {
        f2 rr, gg, bb;
        if (pp == 0) { rr = (f2){r4.x, r4.y}; gg = (f2){g4.x, g4.y}; bb = (f2){b4.x, b4.y}; }
        else         { rr = (f2){r4.z, r4.w}; gg = (f2){g4.z, g4.w}; bb = (f2){b4.z, b4.w}; }

        // ---- guide MLP, packed across the pixel pair ----
        f2 acc = splat2(params[80]);
#pragma unroll
        for (int k = 0; k < 16; ++k) {
            f2 gk = __builtin_elementwise_fma(rr, splat2(params[k]),
                    __builtin_elementwise_fma(gg, splat2(params[16 + k]),
                    __builtin_elementwise_fma(bb, splat2(params[32 + k]),
                                              splat2(params[48 + k]))));
            gk = __builtin_elementwise_max(gk, splat2(0.0f));
            acc = __builtin_elementwise_fma(gk, splat2(params[64 + k]), acc);
        }
        // sigmoid -> z coordinate: zg = 8*sigma(acc) - 0.5
        f2 zg;
        zg.x = fmaf(8.0f, __builtin_amdgcn_rcpf(1.0f + __expf(-acc.x)), -0.5f);
        zg.y = fmaf(8.0f, __builtin_amdgcn_rcpf(1.0f + __expf(-acc.y)), -0.5f);

        f2 Rp, Gp, Bp;
#pragma unroll
        for (int px = 0; px < 2; ++px) {
            const int j = pp * 2 + px;
            const float zgp = px ? zg.y : zg.x;
            int   z0 = (int)floorf(zgp);
            float fz = zgp - (float)z0;
            int zc0 = z0 < 0 ? 0 : z0;
            int zc1 = (z0 + 1) > 7 ? 7 : (z0 + 1);

            const float fw_ = fw0 + (float)j * 0.015625f;
            const float ww0 = 1.0f - fw_;
            const f2 W00 = splat2(ww0 * (1.0f - fz));
            const f2 W01 = splat2(ww0 * fz);
            const f2 W10 = splat2(fw_ * (1.0f - fz));
            const f2 W11 = splat2(fw_ * fz);

            const float4* p00 = (const float4*)(cell0 + zc0 * 12);
            const float4* p01 = (const float4*)(cell0 + zc1 * 12);
            const float4* p10 = (const float4*)(cell1 + zc0 * 12);
            const float4* p11 = (const float4*)(cell1 + zc1 * 12);

            f2 sa[6];   // channel-packed: {s0,s1}..{s10,s11}
#pragma unroll
            for (int q = 0; q < 3; ++q) {
                float4 a = p00[q], c = p01[q], d = p10[q], e = p11[q];
                f2 alo = (f2){a.x, a.y}, ahi = (f2){a.z, a.w};
                f2 clo = (f2){c.x, c.y}, chi = (f2){c.z, c.w};
                f2 dlo = (f2){d.x, d.y}, dhi = (f2){d.z, d.w};
                f2 elo = (f2){e.x, e.y}, ehi = (f2){e.z, e.w};
                sa[2 * q] =
                    __builtin_elementwise_fma(alo, W00,
                    __builtin_elementwise_fma(clo, W01,
                    __builtin_elementwise_fma(dlo, W10, elo * W11)));
                sa[2 * q + 1] =
                    __builtin_elementwise_fma(ahi, W00,
                    __builtin_elementwise_fma(chi, W01,
                    __builtin_elementwise_fma(dhi, W10, ehi * W11)));
            }

            const float rs = px ? rr.y : rr.x;
            const float gs = px ? gg.y : gg.x;
            const float bs = px ? bb.y : bb.x;
            float Rv = fmaf(rs, sa[0].x, fmaf(gs, sa[0].y, fmaf(bs, sa[1].x, sa[4].y)));
            float Gv = fmaf(rs, sa[1].y, fmaf(gs, sa[2].x, fmaf(bs, sa[2].y, sa[5].x)));
            float Bv = fmaf(rs, sa[3].x, fmaf(gs, sa[3].y, fmaf(bs, sa[4].x, sa[5].y)));
            if (px == 0) { Rp.x = Rv; Gp.x = Gv; Bp.x = Bv; }
            else         { Rp.y = Rv; Gp.y = Gv; Bp.y = Bv; }
        }

        // tanh per pair right away (short live ranges -> lower VGPR pressure)
        f2 tR = fast_tanh2(Rp);
        f2 tG = fast_tanh2(Gp);
        f2 tB = fast_tanh2(Bp);
        if (pp == 0) { vR.x = tR.x; vR.y = tR.y; vG.x = tG.x; vG.y = tG.y; vB.x = tB.x; vB.y = tB.y; }
        else         { vR.z = tR.x; vR.w = tR.y; vG.z = tG.x; vG.w = tG.y; vB.z = tB.x; vB.w = tB.y; }
    }

    __builtin_nontemporal_store(vR, (vfloat4*)(out + planeB + (0 << 20) + pixbase));
    __builtin_nontemporal_store(vG, (vfloat4*)(out + planeB + (1 << 20) + pixbase));
    __builtin_nontemporal_store(vB, (vfloat4*)(out + planeB + (2 << 20) + pixbase));
}

extern "C" void kernel_launch(void* const* d_in, const int* in_sizes, int n_in,
                              void* d_out, int out_size, void* d_ws, size_t ws_size,
                              hipStream_t stream) {
    const float* fullres = (const float*)d_in[0];
    const float* lf      = (const float*)d_in[1];
    const float* gf      = (const float*)d_in[2];
    const float* fw      = (const float*)d_in[3];
    const float* fb      = (const float*)d_in[4];
    const float* g1w     = (const float*)d_in[5];
    const float* g1b     = (const float*)d_in[6];
    const float* bng     = (const float*)d_in[7];
    const float* bnb     = (const float*)d_in[8];
    const float* bnm     = (const float*)d_in[9];
    const float* bnv     = (const float*)d_in[10];
    const float* g2w     = (const float*)d_in[11];
    const float* g2b     = (const float*)d_in[12];
    float* out = (float*)d_out;

    float* gridbuf = (float*)d_ws;
    float* params  = gridbuf + GRIDBUF_FLOATS;

    coeff_kernel<<<4 * 256, 128, 0, stream>>>(lf, gf, fw, fb, g1w, g1b,
                                              bng, bnb, bnm, bnv, g2w, g2b,
                                              gridbuf, params);
    slice_apply_kernel<<<4 * 1024, 256, 0, stream>>>(fullres, gridbuf, params, out);
}

// Round 7
// 129.869 us; speedup vs baseline: 1.2961x; 1.2961x over previous
//
#include <hip/hip_runtime.h>
#include <math.h>

// Problem constants: B=4, H=W=1024, GH=GW=16, GD=8, C=12
// ws layout: gridbuf[((b*16+gh)*16+gw)*96 + z*12 + c], then params[81]
// params: [w_r x16][w_g x16][w_b x16][bias x16][g2w x16][g2b]

#define GRIDBUF_FLOATS (4 * 16 * 16 * 96)
#define CELL_STRIDE 100   // padded from 96: banks shift by 4 per wc

typedef float  vfloat4 __attribute__((ext_vector_type(4)));
typedef float  f2      __attribute__((ext_vector_type(2)));
typedef int    i2      __attribute__((ext_vector_type(2)));

__device__ inline f2 splat2(float x) { f2 v; v.x = x; v.y = x; return v; }

// packed tanh on a pair: t = sign(x) * (1 - 2/(exp(2|x|)+1))
__device__ inline f2 fast_tanh2(f2 x) {
    f2 ax = __builtin_elementwise_abs(x);
    f2 xx = ax + ax;
    f2 e;
    e.x = __expf(xx.x);
    e.y = __expf(xx.y);
    f2 ep1 = e + splat2(1.0f);
    f2 r;
    r.x = __builtin_amdgcn_rcpf(ep1.x);
    r.y = __builtin_amdgcn_rcpf(ep1.y);
    f2 t = splat2(1.0f) - (r + r);          // in [0,1], e=inf -> t=1
    i2 sgn = __builtin_bit_cast(i2, x) & (i2){(int)0x80000000, (int)0x80000000};
    return __builtin_bit_cast(f2, __builtin_bit_cast(i2, t) | sgn);
}

// ---------------- Kernel 1: grid coefficients + folded guide params ----------
__global__ __launch_bounds__(128) void coeff_kernel(
    const float* __restrict__ lf,    // (B,64,16,16)
    const float* __restrict__ gf,    // (B,64)
    const float* __restrict__ fw,    // (96,64)
    const float* __restrict__ fb,    // (96,)
    const float* __restrict__ g1w,   // (16,3)
    const float* __restrict__ g1b,   // (16,)
    const float* __restrict__ bng,
    const float* __restrict__ bnb,
    const float* __restrict__ bnm,
    const float* __restrict__ bnv,
    const float* __restrict__ g2w,   // (1,16)
    const float* __restrict__ g2b,   // (1,)
    float* __restrict__ gridbuf,     // (B,16,16,96)
    float* __restrict__ params)      // 81 floats
{
    __shared__ float fused[64];
    const int blk = blockIdx.x;       // b*256 + pos
    const int b   = blk >> 8;
    const int pos = blk & 255;
    const int t   = threadIdx.x;

    if (t < 64) {
        float v = lf[(b * 64 + t) * 256 + pos] + gf[b * 64 + t];
        fused[t] = v > 0.0f ? v : 0.0f;
    }
    __syncthreads();

    if (t < 96) {
        float acc = fb[t];
        const float* wrow = fw + t * 64;
#pragma unroll
        for (int i = 0; i < 64; ++i) acc = fmaf(wrow[i], fused[i], acc);
        gridbuf[blk * 96 + t] = acc;
    }

    if (blk == 0 && t >= 96 && t < 112) {
        int k = t - 96;
        float a = bng[k] * rsqrtf(bnv[k] + 1e-5f);
        params[k]      = g1w[k * 3 + 0] * a;
        params[16 + k] = g1w[k * 3 + 1] * a;
        params[32 + k] = g1w[k * 3 + 2] * a;
        params[48 + k] = (g1b[k] - bnm[k]) * a + bnb[k];
        params[64 + k] = g2w[k];
        if (k == 0) params[80] = g2b[0];
    }
}

// ---------------- Kernel 2: guide + bilateral slice + apply + tanh -----------
// 8192 blocks x 256 threads: one block = HALF an image row, 2 px/thread.
// Small per-thread working set -> low VGPR (target <=64, no forced cap: R6
// showed forcing 8 waves/EU spills). Fill stages only the 9 grid cells this
// half-row needs (one float4 per thread, single iteration).
__global__ __launch_bounds__(256) void slice_apply_kernel(
    const float* __restrict__ fullres,  // (B,3,1024,1024)
    const float* __restrict__ gridbuf,  // (B,16,16,96)
    const float* __restrict__ params,   // 81 floats (uniform -> s_load)
    float* __restrict__ out)            // (B,3,1024,1024)
{
    __shared__ __align__(16) float hrow[16 * CELL_STRIDE];  // padded h-lerped row

    const int t    = threadIdx.x;
    const int blk  = blockIdx.x;
    const int b    = blk >> 11;
    const int rem  = blk & 2047;
    const int y    = rem >> 1;
    const int half = rem & 1;
    const int x0   = half << 9;

    const int xb      = x0 + (t << 1);           // 2 pixels per thread
    const int pixbase = (y << 10) + xb;
    const int planeB  = (b * 3) << 20;

    // issue pixel loads early (in flight during fill + barrier)
    f2 rr = *(const f2*)(fullres + planeB + (0 << 20) + pixbase);
    f2 gg = *(const f2*)(fullres + planeB + (1 << 20) + pixbase);
    f2 bb = *(const f2*)(fullres + planeB + (2 << 20) + pixbase);

    // ---- fill: 9 cells (cbase..cbase+8) cover this half-row's w-span ----
    {
        const int h0i  = (y < 32) ? -1 : ((y - 32) >> 6);
        const float fh = ((float)y * 0.015625f + (0.0078125f - 0.5f)) - (float)h0i;
        const int hc0  = h0i < 0 ? 0 : h0i;
        const int hc1  = (h0i + 1) > 15 ? 15 : (h0i + 1);
        const float* row0 = gridbuf + (b * 256 + hc0 * 16) * 96;
        const float* row1 = gridbuf + (b * 256 + hc1 * 16) * 96;
        const float wfh0 = 1.0f - fh;
        const int cbase = half * 7;              // half0: cells 0..8, half1: 7..15
        if (t < 216) {                            // 9 cells * 96 floats / 4
            const int i   = cbase * 96 + (t << 2);
            const int wc  = i / 96;
            const int rm  = i - wc * 96;
            float4 a = *(const float4*)(row0 + i);
            float4 c = *(const float4*)(row1 + i);
            float4 r;
            r.x = fmaf(wfh0, a.x, fh * c.x);
            r.y = fmaf(wfh0, a.y, fh * c.y);
            r.z = fmaf(wfh0, a.z, fh * c.z);
            r.w = fmaf(wfh0, a.w, fh * c.w);
            *(float4*)(hrow + wc * CELL_STRIDE + rm) = r;
        }
    }
    __syncthreads();

    // w cells: shared by both pixels (boundaries at x=32+64k are even; xb even)
    const int w0i = (xb < 32) ? -1 : ((xb - 32) >> 6);
    const int wc0 = w0i < 0 ? 0 : w0i;
    const int wc1 = (w0i + 1) > 15 ? 15 : (w0i + 1);
    const float fw0 = (float)xb * 0.015625f + (0.0078125f - 0.5f) - (float)w0i;
    const float* cell0 = hrow + wc0 * CELL_STRIDE;
    const float* cell1 = hrow + wc1 * CELL_STRIDE;

    // ---- guide MLP, packed across the pixel pair ----
    f2 acc = splat2(params[80]);
#pragma unroll
    for (int k = 0; k < 16; ++k) {
        f2 gk = __builtin_elementwise_fma(rr, splat2(params[k]),
                __builtin_elementwise_fma(gg, splat2(params[16 + k]),
                __builtin_elementwise_fma(bb, splat2(params[32 + k]),
                                          splat2(params[48 + k]))));
        gk = __builtin_elementwise_max(gk, splat2(0.0f));
        acc = __builtin_elementwise_fma(gk, splat2(params[64 + k]), acc);
    }
    // sigmoid -> z coordinate: zg = 8*sigma(acc) - 0.5
    f2 zg;
    zg.x = fmaf(8.0f, __builtin_amdgcn_rcpf(1.0f + __expf(-acc.x)), -0.5f);
    zg.y = fmaf(8.0f, __builtin_amdgcn_rcpf(1.0f + __expf(-acc.y)), -0.5f);

    f2 Rp, Gp, Bp;
#pragma unroll
    for (int px = 0; px < 2; ++px) {
        const float zgp = px ? zg.y : zg.x;
        int   z0 = (int)floorf(zgp);
        float fz = zgp - (float)z0;
        int zc0 = z0 < 0 ? 0 : z0;
        int zc1 = (z0 + 1) > 7 ? 7 : (z0 + 1);

        const float fw_ = fw0 + (float)px * 0.015625f;
        const float ww0 = 1.0f - fw_;
        const f2 W00 = splat2(ww0 * (1.0f - fz));
        const f2 W01 = splat2(ww0 * fz);
        const f2 W10 = splat2(fw_ * (1.0f - fz));
        const f2 W11 = splat2(fw_ * fz);

        const float4* p00 = (const float4*)(cell0 + zc0 * 12);
        const float4* p01 = (const float4*)(cell0 + zc1 * 12);
        const float4* p10 = (const float4*)(cell1 + zc0 * 12);
        const float4* p11 = (const float4*)(cell1 + zc1 * 12);

        f2 sa[6];   // channel-packed: {s0,s1}..{s10,s11}
#pragma unroll
        for (int q = 0; q < 3; ++q) {
            float4 a = p00[q], c = p01[q], d = p10[q], e = p11[q];
            f2 alo = (f2){a.x, a.y}, ahi = (f2){a.z, a.w};
            f2 clo = (f2){c.x, c.y}, chi = (f2){c.z, c.w};
            f2 dlo = (f2){d.x, d.y}, dhi = (f2){d.z, d.w};
            f2 elo = (f2){e.x, e.y}, ehi = (f2){e.z, e.w};
            sa[2 * q] =
                __builtin_elementwise_fma(alo, W00,
                __builtin_elementwise_fma(clo, W01,
                __builtin_elementwise_fma(dlo, W10, elo * W11)));
            sa[2 * q + 1] =
                __builtin_elementwise_fma(ahi, W00,
                __builtin_elementwise_fma(chi, W01,
                __builtin_elementwise_fma(dhi, W10, ehi * W11)));
        }

        const float rs = px ? rr.y : rr.x;
        const float gs = px ? gg.y : gg.x;
        const float bs = px ? bb.y : bb.x;
        float Rv = fmaf(rs, sa[0].x, fmaf(gs, sa[0].y, fmaf(bs, sa[1].x, sa[4].y)));
        float Gv = fmaf(rs, sa[1].y, fmaf(gs, sa[2].x, fmaf(bs, sa[2].y, sa[5].x)));
        float Bv = fmaf(rs, sa[3].x, fmaf(gs, sa[3].y, fmaf(bs, sa[4].x, sa[5].y)));
        if (px == 0) { Rp.x = Rv; Gp.x = Gv; Bp.x = Bv; }
        else         { Rp.y = Rv; Gp.y = Gv; Bp.y = Bv; }
    }

    f2 tR = fast_tanh2(Rp);
    f2 tG = fast_tanh2(Gp);
    f2 tB = fast_tanh2(Bp);

    __builtin_nontemporal_store(tR, (f2*)(out + planeB + (0 << 20) + pixbase));
    __builtin_nontemporal_store(tG, (f2*)(out + planeB + (1 << 20) + pixbase));
    __builtin_nontemporal_store(tB, (f2*)(out + planeB + (2 << 20) + pixbase));
}

extern "C" void kernel_launch(void* const* d_in, const int* in_sizes, int n_in,
                              void* d_out, int out_size, void* d_ws, size_t ws_size,
                              hipStream_t stream) {
    const float* fullres = (const float*)d_in[0];
    const float* lf      = (const float*)d_in[1];
    const float* gf      = (const float*)d_in[2];
    const float* fw      = (const float*)d_in[3];
    const float* fb      = (const float*)d_in[4];
    const float* g1w     = (const float*)d_in[5];
    const float* g1b     = (const float*)d_in[6];
    const float* bng     = (const float*)d_in[7];
    const float* bnb     = (const float*)d_in[8];
    const float* bnm     = (const float*)d_in[9];
    const float* bnv     = (const float*)d_in[10];
    const float* g2w     = (const float*)d_in[11];
    const float* g2b     = (const float*)d_in[12];
    float* out = (float*)d_out;

    float* gridbuf = (float*)d_ws;
    float* params  = gridbuf + GRIDBUF_FLOATS;

    coeff_kernel<<<4 * 256, 128, 0, stream>>>(lf, gf, fw, fb, g1w, g1b,
                                              bng, bnb, bnm, bnv, g2w, g2b,
                                              gridbuf, params);
    slice_apply_kernel<<<4 * 2048, 256, 0, stream>>>(fullres, gridbuf, params, out);
}